// Round 1
// baseline (662.372 us; speedup 1.0000x reference)
//
#include <hip/hip_runtime.h>
#include <math.h>

#define MROWS 12544        // B*N = 64*196
#define KDIM  768
#define EMB   32
#define NCODE 8192
#define ZQ_ELEMS 401408    // 64*32*14*14

// ---------------------------------------------------------------------------
// K0: normalize codebook rows; also store ||e||^2 (post-normalization, as ref)
// ---------------------------------------------------------------------------
__global__ __launch_bounds__(256) void k0_norm_codebook(
    const float* __restrict__ cb, float* __restrict__ em, float* __restrict__ n2)
{
    const int t = threadIdx.x;
    const int c = t & 31;
    const int r = blockIdx.x * 8 + (t >> 5);
    float v = cb[r * 32 + c];
    float s = v * v;
    #pragma unroll
    for (int off = 16; off; off >>= 1) s += __shfl_xor(s, off, 32);
    float e = v / sqrtf(s + 1e-12f);
    em[r * 32 + c] = e;
    float s2 = e * e;
    #pragma unroll
    for (int off = 16; off; off >>= 1) s2 += __shfl_xor(s2, off, 32);
    if (c == 0) n2[r] = s2;
}

// ---------------------------------------------------------------------------
// K1: H = tanh(X @ W1^T + b1).  X: 12544x768 row-major, W1: 768x768 row-major.
// 128x128 tile, BK=16, 256 threads, 8x8 micro-tile, double-buffered LDS.
// LDS stride 132 (pad 4) -> conflict-free transposed stores.
// ---------------------------------------------------------------------------
#define BM 128
#define BN 128
#define BK 16
#define LDP 132

__global__ __launch_bounds__(256) void k1_gemm_tanh(
    const float* __restrict__ A, const float* __restrict__ W,
    const float* __restrict__ bias, float* __restrict__ H)
{
    __shared__ __align__(16) float As[2][BK][LDP];
    __shared__ __align__(16) float Bs[2][BK][LDP];

    const int t    = threadIdx.x;
    const int row0 = blockIdx.x * BM;
    const int col0 = blockIdx.y * BN;
    const int tr   = t >> 4;          // 0..15
    const int tc   = t & 15;          // 0..15

    const int lm = t >> 2;            // 0..63
    const int lq = (t & 3) * 4;       // 0,4,8,12

    const float* Ap0 = A + (size_t)(row0 + lm) * KDIM + lq;
    const float* Ap1 = A + (size_t)(row0 + lm + 64) * KDIM + lq;
    const float* Bp0 = W + (size_t)(col0 + lm) * KDIM + lq;
    const float* Bp1 = W + (size_t)(col0 + lm + 64) * KDIM + lq;

    float acc[8][8];
    #pragma unroll
    for (int i = 0; i < 8; ++i)
        #pragma unroll
        for (int j = 0; j < 8; ++j) acc[i][j] = 0.f;

    // preload tile 0
    {
        float4 a0 = *(const float4*)(Ap0);
        float4 a1 = *(const float4*)(Ap1);
        float4 b0 = *(const float4*)(Bp0);
        float4 b1 = *(const float4*)(Bp1);
        As[0][lq+0][lm] = a0.x; As[0][lq+1][lm] = a0.y; As[0][lq+2][lm] = a0.z; As[0][lq+3][lm] = a0.w;
        As[0][lq+0][lm+64] = a1.x; As[0][lq+1][lm+64] = a1.y; As[0][lq+2][lm+64] = a1.z; As[0][lq+3][lm+64] = a1.w;
        Bs[0][lq+0][lm] = b0.x; Bs[0][lq+1][lm] = b0.y; Bs[0][lq+2][lm] = b0.z; Bs[0][lq+3][lm] = b0.w;
        Bs[0][lq+0][lm+64] = b1.x; Bs[0][lq+1][lm+64] = b1.y; Bs[0][lq+2][lm+64] = b1.z; Bs[0][lq+3][lm+64] = b1.w;
    }
    __syncthreads();

    const int nkt = KDIM / BK;   // 48
    int buf = 0;
    for (int kt = 0; kt < nkt; ++kt) {
        float4 na0, na1, nb0, nb1;
        const bool pf = (kt + 1 < nkt);
        if (pf) {
            const int ko = (kt + 1) * BK;
            na0 = *(const float4*)(Ap0 + ko);
            na1 = *(const float4*)(Ap1 + ko);
            nb0 = *(const float4*)(Bp0 + ko);
            nb1 = *(const float4*)(Bp1 + ko);
        }
        #pragma unroll
        for (int k = 0; k < BK; ++k) {
            float4 av0 = *(const float4*)&As[buf][k][tr * 8];
            float4 av1 = *(const float4*)&As[buf][k][tr * 8 + 4];
            float4 bv0 = *(const float4*)&Bs[buf][k][tc * 8];
            float4 bv1 = *(const float4*)&Bs[buf][k][tc * 8 + 4];
            float a_[8] = {av0.x, av0.y, av0.z, av0.w, av1.x, av1.y, av1.z, av1.w};
            float b_[8] = {bv0.x, bv0.y, bv0.z, bv0.w, bv1.x, bv1.y, bv1.z, bv1.w};
            #pragma unroll
            for (int i = 0; i < 8; ++i)
                #pragma unroll
                for (int j = 0; j < 8; ++j)
                    acc[i][j] = fmaf(a_[i], b_[j], acc[i][j]);
        }
        if (pf) {
            const int nb = buf ^ 1;
            As[nb][lq+0][lm] = na0.x; As[nb][lq+1][lm] = na0.y; As[nb][lq+2][lm] = na0.z; As[nb][lq+3][lm] = na0.w;
            As[nb][lq+0][lm+64] = na1.x; As[nb][lq+1][lm+64] = na1.y; As[nb][lq+2][lm+64] = na1.z; As[nb][lq+3][lm+64] = na1.w;
            Bs[nb][lq+0][lm] = nb0.x; Bs[nb][lq+1][lm] = nb0.y; Bs[nb][lq+2][lm] = nb0.z; Bs[nb][lq+3][lm] = nb0.w;
            Bs[nb][lq+0][lm+64] = nb1.x; Bs[nb][lq+1][lm+64] = nb1.y; Bs[nb][lq+2][lm+64] = nb1.z; Bs[nb][lq+3][lm+64] = nb1.w;
        }
        __syncthreads();
        buf ^= 1;
    }

    float bc[8];
    #pragma unroll
    for (int j = 0; j < 8; ++j) bc[j] = bias[col0 + tc * 8 + j];
    #pragma unroll
    for (int i = 0; i < 8; ++i) {
        const int row = row0 + tr * 8 + i;
        float o[8];
        #pragma unroll
        for (int j = 0; j < 8; ++j) o[j] = tanhf(acc[i][j] + bc[j]);
        *(float4*)&H[(size_t)row * KDIM + col0 + tc * 8]     = make_float4(o[0], o[1], o[2], o[3]);
        *(float4*)&H[(size_t)row * KDIM + col0 + tc * 8 + 4] = make_float4(o[4], o[5], o[6], o[7]);
    }
}

// ---------------------------------------------------------------------------
// K2: Z = l2norm(H @ W2^T + b2).  128 rows/block (98 blocks), K-chunks of 64.
// thread: cg=t&7 -> cols cg*4..+3 ; rg=t>>3 -> rows rg+32*rr (rr=0..3)
// ---------------------------------------------------------------------------
#define K2C 64
__global__ __launch_bounds__(256) void k2_gemm_norm(
    const float* __restrict__ H, const float* __restrict__ W2,
    const float* __restrict__ b2, float* __restrict__ Z)
{
    __shared__ __align__(16) float As2[128][K2C + 4];
    __shared__ __align__(16) float Ws2[32][K2C + 4];

    const int t    = threadIdx.x;
    const int row0 = blockIdx.x * 128;
    const int cg   = t & 7;
    const int rg   = t >> 3;

    float acc[4][4];
    #pragma unroll
    for (int i = 0; i < 4; ++i)
        #pragma unroll
        for (int j = 0; j < 4; ++j) acc[i][j] = 0.f;

    for (int kc = 0; kc < KDIM; kc += K2C) {
        __syncthreads();
        #pragma unroll
        for (int i = 0; i < 8; ++i) {
            const int fi = t + 256 * i;
            const int r = fi >> 4, kq = fi & 15;
            *(float4*)&As2[r][kq * 4] = *(const float4*)&H[(size_t)(row0 + r) * KDIM + kc + kq * 4];
        }
        #pragma unroll
        for (int i = 0; i < 2; ++i) {
            const int fi = t + 256 * i;
            const int d = fi >> 4, kq = fi & 15;
            *(float4*)&Ws2[d][kq * 4] = *(const float4*)&W2[(size_t)d * KDIM + kc + kq * 4];
        }
        __syncthreads();
        #pragma unroll
        for (int k4 = 0; k4 < K2C / 4; ++k4) {
            float4 w4[4];
            #pragma unroll
            for (int c = 0; c < 4; ++c) w4[c] = *(const float4*)&Ws2[cg * 4 + c][k4 * 4];
            #pragma unroll
            for (int rr = 0; rr < 4; ++rr) {
                float4 a4 = *(const float4*)&As2[rg + 32 * rr][k4 * 4];
                #pragma unroll
                for (int c = 0; c < 4; ++c) {
                    acc[rr][c] = fmaf(a4.x, w4[c].x, acc[rr][c]);
                    acc[rr][c] = fmaf(a4.y, w4[c].y, acc[rr][c]);
                    acc[rr][c] = fmaf(a4.z, w4[c].z, acc[rr][c]);
                    acc[rr][c] = fmaf(a4.w, w4[c].w, acc[rr][c]);
                }
            }
        }
    }

    float bc[4];
    #pragma unroll
    for (int c = 0; c < 4; ++c) bc[c] = b2[cg * 4 + c];
    #pragma unroll
    for (int rr = 0; rr < 4; ++rr) {
        float h0 = acc[rr][0] + bc[0];
        float h1 = acc[rr][1] + bc[1];
        float h2 = acc[rr][2] + bc[2];
        float h3 = acc[rr][3] + bc[3];
        float s = h0*h0 + h1*h1 + h2*h2 + h3*h3;
        #pragma unroll
        for (int off = 1; off < 8; off <<= 1) s += __shfl_xor(s, off, 8);
        const float den = sqrtf(s + 1e-12f);
        const int r = row0 + rg + 32 * rr;
        *(float4*)&Z[(size_t)r * EMB + cg * 4] = make_float4(h0/den, h1/den, h2/den, h3/den);
    }
}

// ---------------------------------------------------------------------------
// K3: per row argmin_j (||e_j||^2 - 2 z.e_j); token, z_q (B,32,14,14), loss
// 64 rows/block (196 blocks). Code tiles of 128, double-buffered.
// thread: cg=t&15 (codes cg+16*cc), rg=t>>4 (rows rg+16*rr). LDS row pad 36.
// ---------------------------------------------------------------------------
__global__ __launch_bounds__(256) void k3_argmin(
    const float* __restrict__ Z, const float* __restrict__ EM,
    const float* __restrict__ N2, float* __restrict__ tok,
    float* __restrict__ zq, float* __restrict__ part)
{
    __shared__ __align__(16) float Zs[64][36];
    __shared__ __align__(16) float Es[2][128][36];
    __shared__ float Ns[2][128];
    __shared__ int   Ridx[64];
    __shared__ float lred[4];

    const int t    = threadIdx.x;
    const int row0 = blockIdx.x * 64;
    const int cg   = t & 15;
    const int rg   = t >> 4;

    #pragma unroll
    for (int i = 0; i < 2; ++i) {
        const int fi = t + 256 * i;
        const int r = fi >> 3, kq = fi & 7;
        *(float4*)&Zs[r][kq * 4] = *(const float4*)&Z[(size_t)(row0 + r) * EMB + kq * 4];
    }
    #pragma unroll
    for (int i = 0; i < 4; ++i) {
        const int fi = t + 256 * i;
        const int c = fi >> 3, kq = fi & 7;
        *(float4*)&Es[0][c][kq * 4] = *(const float4*)&EM[(size_t)c * EMB + kq * 4];
    }
    if (t < 128) Ns[0][t] = N2[t];
    __syncthreads();

    float minv[4] = {INFINITY, INFINITY, INFINITY, INFINITY};
    int   mini[4] = {0, 0, 0, 0};
    int buf = 0;
    for (int tile = 0; tile < NCODE / 128; ++tile) {
        float4 pe[4];
        float pn = 0.f;
        const bool pf = (tile + 1 < NCODE / 128);
        if (pf) {
            const int base = (tile + 1) * 128;
            #pragma unroll
            for (int i = 0; i < 4; ++i) {
                const int fi = t + 256 * i;
                const int c = fi >> 3, kq = fi & 7;
                pe[i] = *(const float4*)&EM[(size_t)(base + c) * EMB + kq * 4];
            }
            if (t < 128) pn = N2[base + t];
        }
        float dot[4][8];
        #pragma unroll
        for (int rr = 0; rr < 4; ++rr)
            #pragma unroll
            for (int cc = 0; cc < 8; ++cc) dot[rr][cc] = 0.f;

        #pragma unroll
        for (int k4 = 0; k4 < 8; ++k4) {
            float4 z4[4];
            #pragma unroll
            for (int rr = 0; rr < 4; ++rr) z4[rr] = *(const float4*)&Zs[rg + 16 * rr][k4 * 4];
            #pragma unroll
            for (int cc = 0; cc < 8; ++cc) {
                float4 e4 = *(const float4*)&Es[buf][cg + 16 * cc][k4 * 4];
                #pragma unroll
                for (int rr = 0; rr < 4; ++rr) {
                    dot[rr][cc] = fmaf(z4[rr].x, e4.x, dot[rr][cc]);
                    dot[rr][cc] = fmaf(z4[rr].y, e4.y, dot[rr][cc]);
                    dot[rr][cc] = fmaf(z4[rr].z, e4.z, dot[rr][cc]);
                    dot[rr][cc] = fmaf(z4[rr].w, e4.w, dot[rr][cc]);
                }
            }
        }
        #pragma unroll
        for (int cc = 0; cc < 8; ++cc) {
            const int cl = cg + 16 * cc;
            const float n2v = Ns[buf][cl];
            const int gi = tile * 128 + cl;
            #pragma unroll
            for (int rr = 0; rr < 4; ++rr) {
                const float sc = fmaf(-2.f, dot[rr][cc], n2v);
                if (sc < minv[rr]) { minv[rr] = sc; mini[rr] = gi; }
            }
        }
        if (pf) {
            #pragma unroll
            for (int i = 0; i < 4; ++i) {
                const int fi = t + 256 * i;
                const int c = fi >> 3, kq = fi & 7;
                *(float4*)&Es[buf ^ 1][c][kq * 4] = pe[i];
            }
            if (t < 128) Ns[buf ^ 1][t] = pn;
        }
        __syncthreads();
        buf ^= 1;
    }

    // reduce across 16 code-group lanes per row; ties -> smaller index
    #pragma unroll
    for (int rr = 0; rr < 4; ++rr) {
        #pragma unroll
        for (int off = 8; off; off >>= 1) {
            const float ov = __shfl_xor(minv[rr], off, 16);
            const int   oi = __shfl_xor(mini[rr], off, 16);
            if (ov < minv[rr] || (ov == minv[rr] && oi < mini[rr])) {
                minv[rr] = ov; mini[rr] = oi;
            }
        }
        if (cg == 0) Ridx[rg + 16 * rr] = mini[rr];
    }
    __syncthreads();

    if (t < 64) tok[row0 + t] = (float)Ridx[t];

    float lp = 0.f;
    #pragma unroll
    for (int i = 0; i < 8; ++i) {
        const int fi = t + 256 * i;
        const int r = fi >> 5, ch = fi & 31;
        const int m = row0 + r;
        const int idx = Ridx[r];
        const float e = EM[(size_t)idx * EMB + ch];
        const float zv = Zs[r][ch];
        const float d = e - zv;
        lp = fmaf(d, d, lp);
        const int b = m / 196, n = m % 196;
        zq[(size_t)b * 6272 + ch * 196 + n] = e;
    }
    #pragma unroll
    for (int off = 32; off; off >>= 1) lp += __shfl_xor(lp, off, 64);
    if ((t & 63) == 0) lred[t >> 6] = lp;
    __syncthreads();
    if (t == 0) part[blockIdx.x] = lred[0] + lred[1] + lred[2] + lred[3];
}

// ---------------------------------------------------------------------------
// K4: deterministic loss reduce: loss = (sum part) / 401408 (BETA = 1)
// ---------------------------------------------------------------------------
__global__ __launch_bounds__(256) void k4_loss(
    const float* __restrict__ part, float* __restrict__ loss)
{
    const int t = threadIdx.x;
    float v = (t < 196) ? part[t] : 0.f;
    #pragma unroll
    for (int off = 32; off; off >>= 1) v += __shfl_xor(v, off, 64);
    __shared__ float r[4];
    if ((t & 63) == 0) r[t >> 6] = v;
    __syncthreads();
    if (t == 0) loss[0] = (r[0] + r[1] + r[2] + r[3]) * (1.0f / 401408.f);
}

// ---------------------------------------------------------------------------
extern "C" void kernel_launch(void* const* d_in, const int* in_sizes, int n_in,
                              void* d_out, int out_size, void* d_ws, size_t ws_size,
                              hipStream_t stream)
{
    (void)in_sizes; (void)n_in; (void)out_size; (void)ws_size;
    const float* features = (const float*)d_in[0];
    const float* w1 = (const float*)d_in[1];
    const float* b1 = (const float*)d_in[2];
    const float* w2 = (const float*)d_in[3];
    const float* b2 = (const float*)d_in[4];
    const float* cb = (const float*)d_in[5];

    float* out  = (float*)d_out;
    float* tok  = out;                       // 12544
    float* zq   = out + MROWS;               // 401408
    float* loss = out + MROWS + ZQ_ELEMS;    // 1

    float* ws   = (float*)d_ws;
    float* H    = ws;                         // 12544*768
    float* Zb   = H + (size_t)MROWS * KDIM;   // 12544*32
    float* EM   = Zb + (size_t)MROWS * EMB;   // 8192*32
    float* N2   = EM + (size_t)NCODE * EMB;   // 8192
    float* PART = N2 + NCODE;                 // 196

    k0_norm_codebook<<<NCODE / 8, 256, 0, stream>>>(cb, EM, N2);
    k1_gemm_tanh<<<dim3(MROWS / BM, KDIM / BN), 256, 0, stream>>>(features, w1, b1, H);
    k2_gemm_norm<<<MROWS / 128, 256, 0, stream>>>(H, w2, b2, Zb);
    k3_argmin<<<MROWS / 64, 256, 0, stream>>>(Zb, EM, N2, tok, zq, PART);
    k4_loss<<<1, 256, 0, stream>>>(PART, loss);
}